// Round 1
// baseline (203.059 us; speedup 1.0000x reference)
//
#include <hip/hip_runtime.h>
#include <cmath>

#define D 128
#define CHUNK 256                 // members per online-softmax chunk (4 regs/lane)
#define NB (CHUNK / 64)           // sub-blocks of 64 members

__device__ __forceinline__ int lower_bound_i32(const int* __restrict__ a, int n, int v) {
    int lo = 0, hi = n;
    while (lo < hi) {
        int mid = (lo + hi) >> 1;
        if (a[mid] < v) lo = mid + 1; else hi = mid;
    }
    return lo;
}

__global__ __launch_bounds__(128, 4)
void gate_attn_pool_kernel(const float* __restrict__ tf_hs,
                           const float* __restrict__ tf_hf,
                           const float* __restrict__ w_hs,
                           const float* __restrict__ w_hf,
                           const int*   __restrict__ member_idx,
                           const int*   __restrict__ segment_ids,
                           float* __restrict__ out,
                           int E, int G) {
    const int g    = blockIdx.x;
    const int wid  = threadIdx.x >> 6;   // wave 0 -> hs, wave 1 -> hf
    const int lane = threadIdx.x & 63;

    const float2* tok = (const float2*)(wid ? tf_hf : tf_hs);  // [N][64] float2
    const float2* wv  = (const float2*)(wid ? w_hf  : w_hs);   // [64] float2
    float2* orow = (float2*)(out + ((size_t)wid * G + g) * D); // [64] float2

    // contiguous member range of this gate (segment_ids sorted ascending)
    const int start = lower_bound_i32(segment_ids, E, g);
    const int end   = lower_bound_i32(segment_ids, E, g + 1);

    const float2 wl = wv[lane];

    float m = -INFINITY;          // running max   (uniform across lanes)
    float z = 0.f;                // running sum p (uniform across lanes)
    float2 acc = make_float2(0.f, 0.f);  // running sum p*x, this lane's 2 dims

    for (int cs = start; cs < end; cs += CHUNK) {
        const int ccnt = min(CHUNK, end - cs);

        // stage member row indices for the chunk (lane-parallel, no per-member idx loads)
        int rowreg[NB];
        #pragma unroll
        for (int b = 0; b < NB; ++b) {
            const int e = cs + b * 64 + lane;
            rowreg[b] = (e < end) ? member_idx[e] : 0;
        }

        // pass 1: logits (wave-cooperative dot) + chunk max; logits kept in regs
        float lreg[NB];
        float cmax = -INFINITY;
        #pragma unroll
        for (int b = 0; b < NB; ++b) {
            lreg[b] = 0.f;
            const int jn = min(64, ccnt - b * 64);
            for (int j = 0; j < jn; ++j) {
                const int row = __shfl(rowreg[b], j);
                const float2 x = tok[row * 64 + lane];          // coalesced 512B/row
                float part = x.x * wl.x + x.y * wl.y;
                #pragma unroll
                for (int o = 32; o; o >>= 1) part += __shfl_xor(part, o);
                if (lane == j) lreg[b] = part;                  // lane j owns member b*64+j
                cmax = fmaxf(cmax, part);
            }
        }

        // online-softmax rescale of running state
        const float nm = fmaxf(m, cmax);
        const float scale = (m == -INFINITY) ? 0.f : __expf(m - nm);
        z *= scale; acc.x *= scale; acc.y *= scale;
        m = nm;

        // pass 2: p = exp(logit - m); z += p; acc += p * x  (rows L2-hot)
        #pragma unroll
        for (int b = 0; b < NB; ++b) {
            const int jn = min(64, ccnt - b * 64);
            for (int j = 0; j < jn; ++j) {
                const float logit = __shfl(lreg[b], j);
                const float p = __expf(logit - m);
                z += p;
                const int row = __shfl(rowreg[b], j);
                const float2 x = tok[row * 64 + lane];
                acc.x = fmaf(p, x.x, acc.x);
                acc.y = fmaf(p, x.y, acc.y);
            }
        }
    }

    // out = (sum p*x) / max(sum p, 1e-9); empty segment -> acc=0 -> writes zeros
    const float inv = 1.f / fmaxf(z, 1e-9f);
    orow[lane] = make_float2(acc.x * inv, acc.y * inv);
}

extern "C" void kernel_launch(void* const* d_in, const int* in_sizes, int n_in,
                              void* d_out, int out_size, void* d_ws, size_t ws_size,
                              hipStream_t stream) {
    const float* tf_hs = (const float*)d_in[0];
    const float* tf_hf = (const float*)d_in[1];
    const float* w_hs  = (const float*)d_in[2];
    const float* w_hf  = (const float*)d_in[3];
    const int* member_idx  = (const int*)d_in[4];
    const int* segment_ids = (const int*)d_in[5];
    float* out = (float*)d_out;

    const int E = in_sizes[4];
    const int G = out_size / (2 * D);   // outputs: hop_hs [G,D] then hop_hf [G,D]

    gate_attn_pool_kernel<<<G, 128, 0, stream>>>(
        tf_hs, tf_hf, w_hs, w_hf, member_idx, segment_ids, out, E, G);
}

// Round 2
// 128.045 us; speedup vs baseline: 1.5858x; 1.5858x over previous
//
#include <hip/hip_runtime.h>
#include <cmath>

#define D 128

// ---------------- kernel 1: logits[n] = tok[n] . w (both pools) ----------------
__global__ __launch_bounds__(256, 4)
void logits_kernel(const float* __restrict__ tf_hs,
                   const float* __restrict__ tf_hf,
                   const float* __restrict__ w_hs,
                   const float* __restrict__ w_hf,
                   float* __restrict__ logit_hs,
                   float* __restrict__ logit_hf,
                   int N) {
    const int lane   = threadIdx.x & 63;
    const int nwaves = (gridDim.x * blockDim.x) >> 6;
    const int w0     = (blockIdx.x * blockDim.x + threadIdx.x) >> 6;

    const float2 whs = ((const float2*)w_hs)[lane];
    const float2 whf = ((const float2*)w_hf)[lane];
    const float2* ths = (const float2*)tf_hs;
    const float2* thf = (const float2*)tf_hf;

    for (int r = w0; r < N; r += nwaves) {
        const float2 xh = ths[(size_t)r * 64 + lane];
        const float2 xf = thf[(size_t)r * 64 + lane];
        float ph = xh.x * whs.x + xh.y * whs.y;
        float pf = xf.x * whf.x + xf.y * whf.y;
        #pragma unroll
        for (int o = 32; o; o >>= 1) {
            ph += __shfl_xor(ph, o);
            pf += __shfl_xor(pf, o);
        }
        if (lane == 0) { logit_hs[r] = ph; logit_hf[r] = pf; }
    }
}

// ---------------- kernel 0b: starts[g] = lower_bound(seg, g), starts[G] = E ----
__global__ void starts_kernel(const int* __restrict__ seg,
                              int* __restrict__ starts, int E, int G) {
    const int e = blockIdx.x * blockDim.x + threadIdx.x;
    if (e >= E) return;
    const int s = seg[e];
    if (e == 0) {
        for (int g = 0; g <= s; ++g) starts[g] = 0;
    } else {
        const int sp = seg[e - 1];
        for (int g = sp + 1; g <= s; ++g) starts[g] = e;
    }
    if (e == E - 1) {
        for (int g = s + 1; g <= G; ++g) starts[g] = E;
    }
}

// ---------------- kernel 2: per-gate softmax-weighted row sum ------------------
__global__ __launch_bounds__(256, 4)
void pool_kernel(const float* __restrict__ tf_hs,
                 const float* __restrict__ tf_hf,
                 const float* __restrict__ logit_hs,
                 const float* __restrict__ logit_hf,
                 const int* __restrict__ member_idx,
                 const int* __restrict__ starts,
                 float* __restrict__ out, int G) {
    const int wid  = threadIdx.x >> 6;
    const int lane = threadIdx.x & 63;
    const int gate = blockIdx.x * (blockDim.x >> 6) + wid;
    if (gate >= G) return;

    const int start = starts[gate];
    const int end   = starts[gate + 1];

    const float2* ths = (const float2*)tf_hs;
    const float2* thf = (const float2*)tf_hf;

    // pass A: per-gate max over logits (lane-strided gather, 4B L2-resident)
    float mh = -INFINITY, mf = -INFINITY;
    for (int e = start + lane; e < end; e += 64) {
        const int row = member_idx[e];
        mh = fmaxf(mh, logit_hs[row]);
        mf = fmaxf(mf, logit_hf[row]);
    }
    #pragma unroll
    for (int o = 32; o; o >>= 1) {
        mh = fmaxf(mh, __shfl_xor(mh, o));
        mf = fmaxf(mf, __shfl_xor(mf, o));
    }

    // pass B: z = sum exp(logit - m)
    float zh = 0.f, zf = 0.f;
    for (int e = start + lane; e < end; e += 64) {
        const int row = member_idx[e];
        zh += __expf(logit_hs[row] - mh);
        zf += __expf(logit_hf[row] - mf);
    }
    #pragma unroll
    for (int o = 32; o; o >>= 1) {
        zh += __shfl_xor(zh, o);
        zf += __shfl_xor(zf, o);
    }
    const float izh = 1.f / fmaxf(zh, 1e-9f);
    const float izf = 1.f / fmaxf(zf, 1e-9f);

    // pass C: acc = sum attn_e * x_e  (8-deep pipelined row gathers)
    float2 ah = make_float2(0.f, 0.f), af = make_float2(0.f, 0.f);
    for (int base = start; base < end; base += 64) {
        const int e = base + lane;
        const bool valid = e < end;
        const int row = valid ? member_idx[e] : 0;
        const float ph = valid ? __expf(logit_hs[row] - mh) * izh : 0.f;
        const float pf = valid ? __expf(logit_hf[row] - mf) * izf : 0.f;
        const int jn = min(64, end - base);
        for (int j0 = 0; j0 < jn; j0 += 8) {
            int   rr[8]; float phh[8], pff[8];
            float2 xh[8], xf[8];
            #pragma unroll
            for (int k = 0; k < 8; ++k) {
                rr[k]  = __shfl(row, j0 + k);
                phh[k] = __shfl(ph,  j0 + k);
                pff[k] = __shfl(pf,  j0 + k);
            }
            #pragma unroll
            for (int k = 0; k < 8; ++k) {
                xh[k] = ths[(size_t)rr[k] * 64 + lane];
                xf[k] = thf[(size_t)rr[k] * 64 + lane];
            }
            #pragma unroll
            for (int k = 0; k < 8; ++k) {
                ah.x = fmaf(phh[k], xh[k].x, ah.x);
                ah.y = fmaf(phh[k], xh[k].y, ah.y);
                af.x = fmaf(pff[k], xf[k].x, af.x);
                af.y = fmaf(pff[k], xf[k].y, af.y);
            }
        }
    }

    float2* oh = (float2*)(out + (size_t)gate * D);
    float2* of = (float2*)(out + ((size_t)G + gate) * D);
    oh[lane] = ah;
    of[lane] = af;
}

extern "C" void kernel_launch(void* const* d_in, const int* in_sizes, int n_in,
                              void* d_out, int out_size, void* d_ws, size_t ws_size,
                              hipStream_t stream) {
    const float* tf_hs = (const float*)d_in[0];
    const float* tf_hf = (const float*)d_in[1];
    const float* w_hs  = (const float*)d_in[2];
    const float* w_hf  = (const float*)d_in[3];
    const int* member_idx  = (const int*)d_in[4];
    const int* segment_ids = (const int*)d_in[5];
    float* out = (float*)d_out;

    const int N = in_sizes[0] / D;
    const int E = in_sizes[4];
    const int G = out_size / (2 * D);

    float* logit_hs = (float*)d_ws;           // [N]
    float* logit_hf = logit_hs + N;           // [N]
    int*   starts   = (int*)(logit_hf + N);   // [G+1]

    logits_kernel<<<2048, 256, 0, stream>>>(tf_hs, tf_hf, w_hs, w_hf,
                                            logit_hs, logit_hf, N);
    starts_kernel<<<(E + 255) / 256, 256, 0, stream>>>(segment_ids, starts, E, G);
    pool_kernel<<<(G + 3) / 4, 256, 0, stream>>>(tf_hs, tf_hf, logit_hs, logit_hf,
                                                 member_idx, starts, out, G);
}

// Round 3
// 119.248 us; speedup vs baseline: 1.7028x; 1.0738x over previous
//
#include <hip/hip_runtime.h>
#include <cmath>

#define D 128

// ---------------- kernel 1: logits[n] = tok[n] . w (both pools) ----------------
__global__ __launch_bounds__(256, 4)
void logits_kernel(const float* __restrict__ tf_hs,
                   const float* __restrict__ tf_hf,
                   const float* __restrict__ w_hs,
                   const float* __restrict__ w_hf,
                   float* __restrict__ logit_hs,
                   float* __restrict__ logit_hf,
                   int N) {
    const int lane   = threadIdx.x & 63;
    const int nwaves = (gridDim.x * blockDim.x) >> 6;
    const int w0     = (blockIdx.x * blockDim.x + threadIdx.x) >> 6;

    const float2 whs = ((const float2*)w_hs)[lane];
    const float2 whf = ((const float2*)w_hf)[lane];
    const float2* ths = (const float2*)tf_hs;
    const float2* thf = (const float2*)tf_hf;

    for (int r = w0; r < N; r += nwaves) {
        const float2 xh = ths[(size_t)r * 64 + lane];
        const float2 xf = thf[(size_t)r * 64 + lane];
        float ph = xh.x * whs.x + xh.y * whs.y;
        float pf = xf.x * whf.x + xf.y * whf.y;
        #pragma unroll
        for (int o = 32; o; o >>= 1) {
            ph += __shfl_xor(ph, o);
            pf += __shfl_xor(pf, o);
        }
        if (lane == 0) { logit_hs[r] = ph; logit_hf[r] = pf; }
    }
}

// ---------------- kernel 0b: starts[g] = lower_bound(seg, g), starts[G] = E ----
__global__ void starts_kernel(const int* __restrict__ seg,
                              int* __restrict__ starts, int E, int G) {
    const int e = blockIdx.x * blockDim.x + threadIdx.x;
    if (e >= E) return;
    const int s = seg[e];
    if (e == 0) {
        for (int g = 0; g <= s; ++g) starts[g] = 0;
    } else {
        const int sp = seg[e - 1];
        for (int g = sp + 1; g <= s; ++g) starts[g] = e;
    }
    if (e == E - 1) {
        for (int g = s + 1; g <= G; ++g) starts[g] = E;
    }
}

// ---------------- kernel 2: one wave per (gate, pool) --------------------------
__global__ __launch_bounds__(256, 4)
void pool_kernel(const float* __restrict__ tf_hs,
                 const float* __restrict__ tf_hf,
                 const float* __restrict__ logit_hs,
                 const float* __restrict__ logit_hf,
                 const int* __restrict__ member_idx,
                 const int* __restrict__ starts,
                 float* __restrict__ out, int G) {
    const int wid  = threadIdx.x >> 6;
    const int lane = threadIdx.x & 63;
    const int wgid = blockIdx.x * (blockDim.x >> 6) + wid;   // [0, 2G)
    if (wgid >= 2 * G) return;
    const int pool = wgid >= G;
    const int gate = pool ? (wgid - G) : wgid;

    const float2* tok   = (const float2*)(pool ? tf_hf : tf_hs);
    const float*  logit = pool ? logit_hf : logit_hs;

    const int start = starts[gate];
    const int end   = starts[gate + 1];
    const int cnt   = end - start;

    float2 acc = make_float2(0.f, 0.f);

    if (cnt <= 64) {
        // ---- fast path: whole gate in one wave-register chunk ----
        const int  e   = start + lane;
        const bool v   = e < end;
        const int  row = v ? member_idx[e] : 0;
        const float l  = v ? logit[row] : -INFINITY;

        float m = l;
        #pragma unroll
        for (int o = 32; o; o >>= 1) m = fmaxf(m, __shfl_xor(m, o));
        float p = v ? __expf(l - m) : 0.f;
        float z = p;
        #pragma unroll
        for (int o = 32; o; o >>= 1) z += __shfl_xor(z, o);
        const float iz = 1.f / fmaxf(z, 1e-9f);

        for (int j0 = 0; j0 < cnt; j0 += 16) {         // 16-deep load pipeline
            int rj[16]; float pj[16]; float2 x[16];
            #pragma unroll
            for (int k = 0; k < 16; ++k) {
                rj[k] = __shfl(row, j0 + k);           // lanes >= cnt: row=0, p=0
                pj[k] = __shfl(p,   j0 + k);
            }
            #pragma unroll
            for (int k = 0; k < 16; ++k)
                x[k] = tok[(size_t)rj[k] * 64 + lane];
            #pragma unroll
            for (int k = 0; k < 16; ++k) {
                acc.x = fmaf(pj[k], x[k].x, acc.x);
                acc.y = fmaf(pj[k], x[k].y, acc.y);
            }
        }
        acc.x *= iz; acc.y *= iz;
    } else {
        // ---- slow path: online softmax over 64-member chunks ----
        float m = -INFINITY, z = 0.f;
        for (int e0 = start; e0 < end; e0 += 64) {
            const int  e   = e0 + lane;
            const bool v   = e < end;
            const int  row = v ? member_idx[e] : 0;
            const float l  = v ? logit[row] : -INFINITY;
            float cm = l;
            #pragma unroll
            for (int o = 32; o; o >>= 1) cm = fmaxf(cm, __shfl_xor(cm, o));
            const float nm = fmaxf(m, cm);
            z *= __expf(m - nm);                       // m=-INF -> 0*0 = 0
            m = nm;
            float pz = v ? __expf(l - m) : 0.f;
            #pragma unroll
            for (int o = 32; o; o >>= 1) pz += __shfl_xor(pz, o);
            z += pz;
        }
        const float iz = 1.f / fmaxf(z, 1e-9f);

        for (int e0 = start; e0 < end; e0 += 64) {
            const int  e   = e0 + lane;
            const bool v   = e < end;
            const int  row = v ? member_idx[e] : 0;
            const float l  = v ? logit[row] : -INFINITY;
            const float p  = v ? __expf(l - m) : 0.f;
            const int jn = min(64, end - e0);
            for (int j0 = 0; j0 < jn; j0 += 16) {
                int rj[16]; float pj[16]; float2 x[16];
                #pragma unroll
                for (int k = 0; k < 16; ++k) {
                    rj[k] = __shfl(row, j0 + k);
                    pj[k] = __shfl(p,   j0 + k);
                }
                #pragma unroll
                for (int k = 0; k < 16; ++k)
                    x[k] = tok[(size_t)rj[k] * 64 + lane];
                #pragma unroll
                for (int k = 0; k < 16; ++k) {
                    acc.x = fmaf(pj[k], x[k].x, acc.x);
                    acc.y = fmaf(pj[k], x[k].y, acc.y);
                }
            }
        }
        acc.x *= iz; acc.y *= iz;
    }

    float2* orow = (float2*)(out + ((size_t)pool * G + gate) * D);
    orow[lane] = acc;
}

extern "C" void kernel_launch(void* const* d_in, const int* in_sizes, int n_in,
                              void* d_out, int out_size, void* d_ws, size_t ws_size,
                              hipStream_t stream) {
    const float* tf_hs = (const float*)d_in[0];
    const float* tf_hf = (const float*)d_in[1];
    const float* w_hs  = (const float*)d_in[2];
    const float* w_hf  = (const float*)d_in[3];
    const int* member_idx  = (const int*)d_in[4];
    const int* segment_ids = (const int*)d_in[5];
    float* out = (float*)d_out;

    const int N = in_sizes[0] / D;
    const int E = in_sizes[4];
    const int G = out_size / (2 * D);

    float* logit_hs = (float*)d_ws;           // [N]
    float* logit_hf = logit_hs + N;           // [N]
    int*   starts   = (int*)(logit_hf + N);   // [G+1]

    logits_kernel<<<2048, 256, 0, stream>>>(tf_hs, tf_hf, w_hs, w_hf,
                                            logit_hs, logit_hf, N);
    starts_kernel<<<(E + 255) / 256, 256, 0, stream>>>(segment_ids, starts, E, G);

    const int nwaves = 2 * G;
    pool_kernel<<<(nwaves + 3) / 4, 256, 0, stream>>>(tf_hs, tf_hf, logit_hs, logit_hf,
                                                      member_idx, starts, out, G);
}

// Round 4
// 90.720 us; speedup vs baseline: 2.2383x; 1.3145x over previous
//
#include <hip/hip_runtime.h>
#include <cmath>

#define D 128

__device__ __forceinline__ uint pack_bf16_rne(float a, float b) {
    uint ua = __float_as_uint(a);
    uint ub = __float_as_uint(b);
    ua += 0x7fffu + ((ua >> 16) & 1u);          // round-to-nearest-even at bit16
    ub += 0x7fffu + ((ub >> 16) & 1u);
    return (ua >> 16) | (ub & 0xffff0000u);
}

// ---- kernel 1: logits[n] = tok[n].w for both pools, + bf16 table conversion ----
__global__ __launch_bounds__(256)
void logits_conv_kernel(const float* __restrict__ tf_hs,
                        const float* __restrict__ tf_hf,
                        const float* __restrict__ w_hs,
                        const float* __restrict__ w_hf,
                        float* __restrict__ logit_hs,
                        float* __restrict__ logit_hf,
                        uint* __restrict__ bhs,      // [N*64] packed bf16x2 (may be null)
                        uint* __restrict__ bhf,
                        int N) {
    const int lane   = threadIdx.x & 63;
    const int nwaves = (gridDim.x * blockDim.x) >> 6;
    const int w0     = (blockIdx.x * blockDim.x + threadIdx.x) >> 6;

    const float2 whs = ((const float2*)w_hs)[lane];
    const float2 whf = ((const float2*)w_hf)[lane];
    const float2* ths = (const float2*)tf_hs;
    const float2* thf = (const float2*)tf_hf;

    for (int r = w0; r < N; r += nwaves) {
        const float2 xh = ths[(size_t)r * 64 + lane];
        const float2 xf = thf[(size_t)r * 64 + lane];
        if (bhs) {
            bhs[(size_t)r * 64 + lane] = pack_bf16_rne(xh.x, xh.y);
            bhf[(size_t)r * 64 + lane] = pack_bf16_rne(xf.x, xf.y);
        }
        float ph = xh.x * whs.x + xh.y * whs.y;
        float pf = xf.x * whf.x + xf.y * whf.y;
        #pragma unroll
        for (int o = 32; o; o >>= 1) {
            ph += __shfl_xor(ph, o);
            pf += __shfl_xor(pf, o);
        }
        if (lane == 0) { logit_hs[r] = ph; logit_hf[r] = pf; }
    }
}

// ---- kernel 0b: starts[g] ----
__global__ void starts_kernel(const int* __restrict__ seg,
                              int* __restrict__ starts, int E, int G) {
    const int e = blockIdx.x * blockDim.x + threadIdx.x;
    if (e >= E) return;
    const int s = seg[e];
    if (e == 0) {
        for (int g = 0; g <= s; ++g) starts[g] = 0;
    } else {
        const int sp = seg[e - 1];
        for (int g = sp + 1; g <= s; ++g) starts[g] = e;
    }
    if (e == E - 1) {
        for (int g = s + 1; g <= G; ++g) starts[g] = E;
    }
}

// ---- kernel 2 (bf16): one wave per (gate, pool); 32 lanes/row, 2 members/instr ----
__global__ __launch_bounds__(256, 4)
void pool_kernel_bf16(const uint2* __restrict__ bhs,   // [N*32] = 4 bf16 dims/elem
                      const uint2* __restrict__ bhf,
                      const float* __restrict__ logit_hs,
                      const float* __restrict__ logit_hf,
                      const int* __restrict__ member_idx,
                      const int* __restrict__ starts,
                      float* __restrict__ out, int G) {
    const int wid  = threadIdx.x >> 6;
    const int lane = threadIdx.x & 63;
    const int wgid = blockIdx.x * (blockDim.x >> 6) + wid;   // [0, 2G)
    if (wgid >= 2 * G) return;
    const int pool = wgid >= G;
    const int gate = pool ? (wgid - G) : wgid;

    const uint2* tok    = pool ? bhf : bhs;
    const float* logit  = pool ? logit_hf : logit_hs;

    const int start = starts[gate];
    const int end   = starts[gate + 1];
    const int cnt   = end - start;

    const int half = lane >> 5;     // which member of each pair this lane serves
    const int hl   = lane & 31;     // dims 4*hl .. 4*hl+3

    float4 acc = make_float4(0.f, 0.f, 0.f, 0.f);
    float m, iz;

    if (cnt <= 64) {
        // ---- softmax stats in one register chunk ----
        const int  e   = start + lane;
        const bool v   = e < end;
        const int  row = v ? member_idx[e] : 0;
        const float l  = v ? logit[row] : -INFINITY;
        m = l;
        #pragma unroll
        for (int o = 32; o; o >>= 1) m = fmaxf(m, __shfl_xor(m, o));
        float p = v ? __expf(l - m) : 0.f;
        float z = p;
        #pragma unroll
        for (int o = 32; o; o >>= 1) z += __shfl_xor(z, o);
        iz = 1.f / fmaxf(z, 1e-9f);

        // ---- weighted row sum: 16 slots x 2 members per iteration ----
        for (int j0 = 0; j0 < cnt; j0 += 32) {
            int rj[16]; float pj[16]; uint2 x[16];
            #pragma unroll
            for (int k = 0; k < 16; ++k) {
                const int src = j0 + 2 * k + half;           // < 64 always
                rj[k] = __shfl(row, src);                    // invalid -> row 0, p 0
                pj[k] = __shfl(p,   src);
            }
            #pragma unroll
            for (int k = 0; k < 16; ++k)
                x[k] = tok[(size_t)rj[k] * 32 + hl];
            #pragma unroll
            for (int k = 0; k < 16; ++k) {
                acc.x = fmaf(pj[k], __uint_as_float(x[k].x << 16),          acc.x);
                acc.y = fmaf(pj[k], __uint_as_float(x[k].x & 0xffff0000u),  acc.y);
                acc.z = fmaf(pj[k], __uint_as_float(x[k].y << 16),          acc.z);
                acc.w = fmaf(pj[k], __uint_as_float(x[k].y & 0xffff0000u),  acc.w);
            }
        }
    } else {
        // ---- online softmax stats over 64-member chunks ----
        m = -INFINITY; float z = 0.f;
        for (int e0 = start; e0 < end; e0 += 64) {
            const int  e   = e0 + lane;
            const bool v   = e < end;
            const int  row = v ? member_idx[e] : 0;
            const float l  = v ? logit[row] : -INFINITY;
            float cm = l;
            #pragma unroll
            for (int o = 32; o; o >>= 1) cm = fmaxf(cm, __shfl_xor(cm, o));
            const float nm = fmaxf(m, cm);
            z *= __expf(m - nm);
            m = nm;
            float pz = v ? __expf(l - m) : 0.f;
            #pragma unroll
            for (int o = 32; o; o >>= 1) pz += __shfl_xor(pz, o);
            z += pz;
        }
        iz = 1.f / fmaxf(z, 1e-9f);

        for (int e0 = start; e0 < end; e0 += 64) {
            const int  e   = e0 + lane;
            const bool v   = e < end;
            const int  row = v ? member_idx[e] : 0;
            const float l  = v ? logit[row] : -INFINITY;
            const float p  = v ? __expf(l - m) : 0.f;
            const int  jn  = min(64, end - e0);
            for (int j0 = 0; j0 < jn; j0 += 32) {
                int rj[16]; float pj[16]; uint2 x[16];
                #pragma unroll
                for (int k = 0; k < 16; ++k) {
                    const int src = j0 + 2 * k + half;
                    rj[k] = __shfl(row, src);
                    pj[k] = __shfl(p,   src);
                }
                #pragma unroll
                for (int k = 0; k < 16; ++k)
                    x[k] = tok[(size_t)rj[k] * 32 + hl];
                #pragma unroll
                for (int k = 0; k < 16; ++k) {
                    acc.x = fmaf(pj[k], __uint_as_float(x[k].x << 16),          acc.x);
                    acc.y = fmaf(pj[k], __uint_as_float(x[k].x & 0xffff0000u),  acc.y);
                    acc.z = fmaf(pj[k], __uint_as_float(x[k].y << 16),          acc.z);
                    acc.w = fmaf(pj[k], __uint_as_float(x[k].y & 0xffff0000u),  acc.w);
                }
            }
        }
    }

    // combine the two member-groups, normalize, write (lanes 0-31 cover 128 dims)
    acc.x += __shfl_xor(acc.x, 32);
    acc.y += __shfl_xor(acc.y, 32);
    acc.z += __shfl_xor(acc.z, 32);
    acc.w += __shfl_xor(acc.w, 32);
    if (half == 0) {
        float4* orow = (float4*)(out + ((size_t)pool * G + gate) * D);
        orow[hl] = make_float4(acc.x * iz, acc.y * iz, acc.z * iz, acc.w * iz);
    }
}

// ---- fallback f32 pool (round-3 version) ----
__global__ __launch_bounds__(256, 4)
void pool_kernel_f32(const float* __restrict__ tf_hs,
                     const float* __restrict__ tf_hf,
                     const float* __restrict__ logit_hs,
                     const float* __restrict__ logit_hf,
                     const int* __restrict__ member_idx,
                     const int* __restrict__ starts,
                     float* __restrict__ out, int G) {
    const int wid  = threadIdx.x >> 6;
    const int lane = threadIdx.x & 63;
    const int wgid = blockIdx.x * (blockDim.x >> 6) + wid;
    if (wgid >= 2 * G) return;
    const int pool = wgid >= G;
    const int gate = pool ? (wgid - G) : wgid;

    const float2* tok   = (const float2*)(pool ? tf_hf : tf_hs);
    const float*  logit = pool ? logit_hf : logit_hs;

    const int start = starts[gate];
    const int end   = starts[gate + 1];

    float m = -INFINITY, z = 0.f;
    for (int e0 = start; e0 < end; e0 += 64) {
        const int  e   = e0 + lane;
        const bool v   = e < end;
        const int  row = v ? member_idx[e] : 0;
        const float l  = v ? logit[row] : -INFINITY;
        float cm = l;
        #pragma unroll
        for (int o = 32; o; o >>= 1) cm = fmaxf(cm, __shfl_xor(cm, o));
        const float nm = fmaxf(m, cm);
        z *= __expf(m - nm);
        m = nm;
        float pz = v ? __expf(l - m) : 0.f;
        #pragma unroll
        for (int o = 32; o; o >>= 1) pz += __shfl_xor(pz, o);
        z += pz;
    }
    const float izs = 1.f / fmaxf(z, 1e-9f);

    float2 acc = make_float2(0.f, 0.f);
    for (int e0 = start; e0 < end; e0 += 64) {
        const int  e   = e0 + lane;
        const bool v   = e < end;
        const int  row = v ? member_idx[e] : 0;
        const float l  = v ? logit[row] : -INFINITY;
        const float p  = v ? __expf(l - m) : 0.f;
        const int jn = min(64, end - e0);
        for (int j0 = 0; j0 < jn; j0 += 16) {
            int rj[16]; float pj[16]; float2 x[16];
            #pragma unroll
            for (int k = 0; k < 16; ++k) {
                rj[k] = __shfl(row, j0 + k);
                pj[k] = __shfl(p,   j0 + k);
            }
            #pragma unroll
            for (int k = 0; k < 16; ++k)
                x[k] = tok[(size_t)rj[k] * 64 + lane];
            #pragma unroll
            for (int k = 0; k < 16; ++k) {
                acc.x = fmaf(pj[k], x[k].x, acc.x);
                acc.y = fmaf(pj[k], x[k].y, acc.y);
            }
        }
    }
    float2* orow = (float2*)(out + ((size_t)pool * G + gate) * D);
    orow[lane] = make_float2(acc.x * izs, acc.y * izs);
}

extern "C" void kernel_launch(void* const* d_in, const int* in_sizes, int n_in,
                              void* d_out, int out_size, void* d_ws, size_t ws_size,
                              hipStream_t stream) {
    const float* tf_hs = (const float*)d_in[0];
    const float* tf_hf = (const float*)d_in[1];
    const float* w_hs  = (const float*)d_in[2];
    const float* w_hf  = (const float*)d_in[3];
    const int* member_idx  = (const int*)d_in[4];
    const int* segment_ids = (const int*)d_in[5];
    float* out = (float*)d_out;

    const int N = in_sizes[0] / D;
    const int E = in_sizes[4];
    const int G = out_size / (2 * D);

    const size_t bf16_words = (size_t)N * 64;                 // uints per table
    const size_t need = 2 * bf16_words * 4 + 2 * (size_t)N * 4 + (size_t)(G + 1) * 4;
    const int nwaves = 2 * G;

    if (ws_size >= need) {
        uint*  bhs      = (uint*)d_ws;                        // [N*64]
        uint*  bhf      = bhs + bf16_words;                   // [N*64]
        float* logit_hs = (float*)(bhf + bf16_words);         // [N]
        float* logit_hf = logit_hs + N;                       // [N]
        int*   starts   = (int*)(logit_hf + N);               // [G+1]

        logits_conv_kernel<<<2048, 256, 0, stream>>>(tf_hs, tf_hf, w_hs, w_hf,
                                                     logit_hs, logit_hf, bhs, bhf, N);
        starts_kernel<<<(E + 255) / 256, 256, 0, stream>>>(segment_ids, starts, E, G);
        pool_kernel_bf16<<<(nwaves + 3) / 4, 256, 0, stream>>>(
            (const uint2*)bhs, (const uint2*)bhf, logit_hs, logit_hf,
            member_idx, starts, out, G);
    } else {
        float* logit_hs = (float*)d_ws;
        float* logit_hf = logit_hs + N;
        int*   starts   = (int*)(logit_hf + N);

        logits_conv_kernel<<<2048, 256, 0, stream>>>(tf_hs, tf_hf, w_hs, w_hf,
                                                     logit_hs, logit_hf, nullptr, nullptr, N);
        starts_kernel<<<(E + 255) / 256, 256, 0, stream>>>(segment_ids, starts, E, G);
        pool_kernel_f32<<<(nwaves + 3) / 4, 256, 0, stream>>>(
            tf_hs, tf_hf, logit_hs, logit_hf, member_idx, starts, out, G);
    }
}